// Round 1
// baseline (756.154 us; speedup 1.0000x reference)
//
#include <hip/hip_runtime.h>
#include <cstddef>

// Bit-exact OpenBLAS-skylakex (KC=320) fp32 SNN.
// Chain order (verified r3/r4/r5): k ascending, panel folds at k=320/640,
// ((P1+P2)+P3)+b1; LIF literal order; layer2 cur2=mm+b2 then m2*0.25+cur2,
// j ascending.
// r7 = r6 structure (double-buffered xs/ws, ONE barrier per tile, register
// prefetch, nontemporal rec stores) with BROWS 64->32:
//  - grid 512 -> 1024 blocks: occupancy was GRID-capped at 2 blocks/CU
//    (512 blocks / 256 CUs); now 4 blocks/CU = 16 waves/CU.
//  - per-thread tile 4x8 -> 2x8 (acc+cur 32 regs, VGPR ~85 < 128 so
//    4 waves/SIMD are allocatable).
//  - LDS trimmed to ~38.8 KB so 4 blocks fit in 160 KB.
//  - layer-2 remap: og = t>>5 (0..2 active over 96 threads), row = t&31.
// Per-element accumulation chains are IDENTICAL to r6 (only the
// thread->element mapping changed) => bit-exactness preserved.

typedef float f32x4 __attribute__((ext_vector_type(4)));

constexpr int BROWS  = 32;
constexpr int BK     = 16;    // 784 = 49*16; KC=320 folds after tiles 19,39
constexpr int NJ     = 128;
constexpr int KDIM   = 784;
constexpr int NO     = 10;
constexpr int TSTEPS = 20;

__global__ __launch_bounds__(256, 4) void snn_fused(
    const float* __restrict__ x,
    const float* __restrict__ W1,
    const float* __restrict__ b1,
    const float* __restrict__ W2,
    const float* __restrict__ b2,
    float* __restrict__ out,
    int B)
{
    __shared__ alignas(16) float xs[2][BK][36];    // [buf][kk][row(32)+pad]
    __shared__ alignas(16) float ws[2][BK][192];   // [buf][kk][16 chunks * 12]
    __shared__ alignas(16) float4 w2s[NJ][3];      // [j][og]: W2[og*4+c][j]*2^-(j&31)
    __shared__ unsigned smaskW[2][BROWS][17];      // parity row masks
    __shared__ float b2s[12];

    const int t  = threadIdx.x;
    const int tx = t & 15;                         // col group: j = tx*8+jj
    const int ty = t >> 4;                         // row group: r = ty*2+rr
    const int r0 = blockIdx.x * BROWS;

    // ---- one-time staging: W2 (o-transposed, scaled), b2 ----
    for (int e = t; e < NJ * 3; e += 256) {
        int og = e % 3, j = e / 3;
        float sc = __int_as_float((127 - (j & 31)) << 23);   // 2^-(j&31), exact
        float vv[4];
        #pragma unroll
        for (int c = 0; c < 4; ++c) {
            int o = og * 4 + c;
            vv[c] = (o < NO) ? W2[o * NJ + j] * sc : 0.0f;
        }
        float4 v; v.x = vv[0]; v.y = vv[1]; v.z = vv[2]; v.w = vv[3];
        w2s[j][og] = v;
    }
    if (t < 12) b2s[t] = (t < NO) ? b2[t] : 0.0f;

    // ---- phase 1: fp32 GEMM, panel folds at k=320,640 ----
    float acc[2][8], cur[2][8];
    #pragma unroll
    for (int rr = 0; rr < 2; ++rr)
        #pragma unroll
        for (int jj = 0; jj < 8; ++jj) { acc[rr][jj] = 0.0f; cur[rr][jj] = 0.0f; }

    const int xrow = t >> 3, xkf = (t & 7) * 2;    // x stage: row(0..31), 2-k chunk
    const int wj   = t >> 1, wkf = (t & 1) * 8;    // W1 stage: j, 8-k chunk
    const int wco  = wj >> 3, wci = wj & 7;        // chunk / intra
    const float* xrp = x  + (size_t)(r0 + xrow) * KDIM + xkf;
    const float* wrp = W1 + (size_t)wj * KDIM + wkf;

    // preload tile 0 -> regs -> buf 0
    float2 xv = *(const float2*)(xrp);
    float4 wa = *(const float4*)(wrp);
    float4 wb = *(const float4*)(wrp + 4);
    {
        xs[0][xkf][xrow] = xv.x; xs[0][xkf + 1][xrow] = xv.y;
        float* wp0 = &ws[0][wkf][wco * 12 + wci];  // rows wkf..wkf+7, stride 192
        wp0[0]    = wa.x; wp0[192]  = wa.y; wp0[384]  = wa.z; wp0[576]  = wa.w;
        wp0[768]  = wb.x; wp0[960]  = wb.y; wp0[1152] = wb.z; wp0[1344] = wb.w;
    }
    __syncthreads();

    #pragma unroll 1
    for (int tt = 0; tt < 49; ++tt) {
        const int cb = tt & 1;
        if (tt < 48) {                             // prefetch next tile -> regs
            const int k0n = (tt + 1) * BK;
            xv = *(const float2*)(xrp + k0n);
            wa = *(const float4*)(wrp + k0n);
            wb = *(const float4*)(wrp + k0n + 4);
        }
        #pragma unroll
        for (int kk = 0; kk < BK; ++kk) {          // strict ascending k
            float2 xr  = *(const float2*)&xs[cb][kk][ty * 2];
            float4 wva = *(const float4*)&ws[cb][kk][tx * 12];
            float4 wvb = *(const float4*)&ws[cb][kk][tx * 12 + 4];
            float xf[2] = {xr.x, xr.y};
            float wf[8] = {wva.x, wva.y, wva.z, wva.w, wvb.x, wvb.y, wvb.z, wvb.w};
            #pragma unroll
            for (int rr = 0; rr < 2; ++rr)
                #pragma unroll
                for (int jj = 0; jj < 8; ++jj)
                    acc[rr][jj] = fmaf(xf[rr], wf[jj], acc[rr][jj]);
        }
        if (tt == 19) {                            // end panel 1 [0,320)
            #pragma unroll
            for (int rr = 0; rr < 2; ++rr)
                #pragma unroll
                for (int jj = 0; jj < 8; ++jj) { cur[rr][jj] = acc[rr][jj]; acc[rr][jj] = 0.0f; }
        } else if (tt == 39) {                     // end panel 2 [320,640)
            #pragma unroll
            for (int rr = 0; rr < 2; ++rr)
                #pragma unroll
                for (int jj = 0; jj < 8; ++jj) { cur[rr][jj] = cur[rr][jj] + acc[rr][jj]; acc[rr][jj] = 0.0f; }
        }
        if (tt < 48) {                             // store prefetched tile
            const int nb = cb ^ 1;
            xs[nb][xkf][xrow] = xv.x; xs[nb][xkf + 1][xrow] = xv.y;
            float* wp0 = &ws[nb][wkf][wco * 12 + wci];
            wp0[0]    = wa.x; wp0[192]  = wa.y; wp0[384]  = wa.z; wp0[576]  = wa.w;
            wp0[768]  = wb.x; wp0[960]  = wb.y; wp0[1152] = wb.z; wp0[1344] = wb.w;
        }
        __syncthreads();                           // ONE barrier per tile
    }
    {
        const float* b1p = b1 + tx * 8;
        float4 ba = *(const float4*)b1p, bb = *(const float4*)(b1p + 4);
        float bf[8] = {ba.x, ba.y, ba.z, ba.w, bb.x, bb.y, bb.z, bb.w};
        #pragma unroll
        for (int rr = 0; rr < 2; ++rr)
            #pragma unroll
            for (int jj = 0; jj < 8; ++jj)
                cur[rr][jj] = (cur[rr][jj] + acc[rr][jj]) + bf[jj];   // +P3, +b1
    }

    // ---- phase 2: LIF dynamics (nontemporal rec stores) ----
    float mem1[2][8];
    #pragma unroll
    for (int rr = 0; rr < 2; ++rr)
        #pragma unroll
        for (int jj = 0; jj < 8; ++jj) mem1[rr][jj] = 0.0f;

    const int row_l2 = t & 31;                     // layer-2: row (0..31)
    const int og     = t >> 5;                     // o-group; og<3 active
    float m2[4]  = {0.f, 0.f, 0.f, 0.f};
    float cnt[4] = {0.f, 0.f, 0.f, 0.f};
    float* rec = out + (size_t)B * NO;

    #pragma unroll 1
    for (int st = 0; st < TSTEPS; ++st) {
        const int p = st & 1;
        #pragma unroll
        for (int rr = 0; rr < 2; ++rr) {
            unsigned bt = 0;
            float s0[8];
            #pragma unroll
            for (int jj = 0; jj < 8; ++jj) {
                float m = fmaf(mem1[rr][jj], 0.25f, cur[rr][jj]);  // *0.25 exact
                float v = m - 1.0f;
                bool  s = v > 0.0f;
                s0[jj] = s ? 1.0f : 0.0f;
                mem1[rr][jj] = s ? 0.0f : m;
                bt |= s ? (1u << jj) : 0u;
            }
            size_t base = ((size_t)st * B + (size_t)(r0 + ty * 2 + rr)) * NJ + tx * 8;
            f32x4 fa = {s0[0], s0[1], s0[2], s0[3]};
            f32x4 fb = {s0[4], s0[5], s0[6], s0[7]};
            __builtin_nontemporal_store(fa, (f32x4*)&rec[base]);
            __builtin_nontemporal_store(fb, (f32x4*)&rec[base + 4]);
            ((unsigned char*)&smaskW[p][ty * 2 + rr][0])[tx] = (unsigned char)bt;
        }
        __syncthreads();
        if (og < 3) {
            unsigned mw[4];
            #pragma unroll
            for (int w = 0; w < 4; ++w) mw[w] = smaskW[p][row_l2][w];
            float mm[4] = {0.f, 0.f, 0.f, 0.f};
            #pragma unroll
            for (int w = 0; w < 4; ++w) {
                unsigned bits = mw[w];
                #pragma unroll
                for (int b = 0; b < 32; ++b) {     // strict ascending j
                    float f = (float)(bits & (1u << b));      // 0 or 2^b, exact
                    float4 wv = w2s[w * 32 + b][og];          // W2 * 2^-b
                    mm[0] = fmaf(f, wv.x, mm[0]);
                    mm[1] = fmaf(f, wv.y, mm[1]);
                    mm[2] = fmaf(f, wv.z, mm[2]);
                    mm[3] = fmaf(f, wv.w, mm[3]);
                }
            }
            #pragma unroll
            for (int c = 0; c < 4; ++c) {
                float cur2 = mm[c] + b2s[og * 4 + c];   // np: chain + b2
                float nm   = fmaf(m2[c], 0.25f, cur2);  // then decay add (exact mul)
                float v2   = nm - 1.0f;
                bool  s2   = v2 > 0.0f;
                cnt[c] += s2 ? 1.0f : 0.0f;
                m2[c]  = s2 ? 0.0f : nm;
            }
        }
    }

    if (og < 3) {
        #pragma unroll
        for (int c = 0; c < 4; ++c) {
            int o = og * 4 + c;
            if (o < NO) out[(size_t)(r0 + row_l2) * NO + o] = cnt[c];
        }
    }
}

extern "C" void kernel_launch(void* const* d_in, const int* in_sizes, int n_in,
                              void* d_out, int out_size, void* d_ws, size_t ws_size,
                              hipStream_t stream)
{
    const float* x  = (const float*)d_in[0];
    const float* W1 = (const float*)d_in[1];
    const float* b1 = (const float*)d_in[2];
    const float* W2 = (const float*)d_in[3];
    const float* b2 = (const float*)d_in[4];
    float* out = (float*)d_out;
    const int B = in_sizes[0] / KDIM;       // 32768
    snn_fused<<<B / BROWS, 256, 0, stream>>>(x, W1, b1, W2, b2, out, B);
}